// Round 2
// baseline (117.860 us; speedup 1.0000x reference)
//
#include <hip/hip_runtime.h>

#define B 32
#define T 65536
#define S 4
#define EPSF 1e-7f
#define TPB 256
#define CHUNK 2048
#define NCHUNK (T / CHUNK)   // 32 chunks per b -> 1024 blocks
#define NACC 21              // 16 term1 + 4 term2 + 1 vad

__device__ __forceinline__ float wave_reduce_sum(float v) {
    #pragma unroll
    for (int off = 32; off > 0; off >>= 1) v += __shfl_down(v, off, 64);
    return v;
}

__global__ void zero_ws_kernel(float* acc) {
    int i = blockIdx.x * blockDim.x + threadIdx.x;
    if (i < B * NACC) acc[i] = 0.0f;
}

__global__ __launch_bounds__(TPB) void partial_kernel(
    const float4* __restrict__ ps,   // pred_speakers [B,T,4] as float4
    const float*  __restrict__ pv,   // pred_vad [B,T]
    const float4* __restrict__ lb,   // labels [B,T,4] as float4
    const float*  __restrict__ vd,   // vad [B,T]
    const int* __restrict__ len,     // lengths [B] (harness passes int32)
    float* __restrict__ acc)         // [B][NACC]
{
    const int b  = blockIdx.x / NCHUNK;
    const int c  = blockIdx.x % NCHUNK;
    const int t0 = c * CHUNK;
    const int L  = len[b];
    if (t0 >= L) return;                 // uniform per block: prefix mask -> skip loads entirely
    const int tend = min(t0 + CHUNK, L);

    float a1[16];
    float a2[4];
    float av = 0.0f;
    #pragma unroll
    for (int k = 0; k < 16; ++k) a1[k] = 0.0f;
    #pragma unroll
    for (int k = 0; k < 4; ++k)  a2[k] = 0.0f;

    const int base = b * T;
    for (int t = t0 + (int)threadIdx.x; t < tend; t += TPB) {
        const float4 p4 = ps[base + t];
        const float4 l4 = lb[base + t];
        const float p[4] = {p4.x, p4.y, p4.z, p4.w};
        const float l[4] = {l4.x, l4.y, l4.z, l4.w};
        float d[4];
        #pragma unroll
        for (int i = 0; i < 4; ++i) {
            const float pc = fminf(fmaxf(p[i], EPSF), 1.0f - EPSF);
            const float lp = __logf(pc);
            const float lq = __logf(1.0f - pc);
            a2[i] += lq;
            d[i] = lp - lq;
        }
        #pragma unroll
        for (int i = 0; i < 4; ++i)
            #pragma unroll
            for (int j = 0; j < 4; ++j)
                a1[i * 4 + j] = fmaf(d[i], l[j], a1[i * 4 + j]);

        // VAD: vad is exactly 0.0 or 1.0 -> one log via select
        const float pvc = fminf(fmaxf(pv[base + t], EPSF), 1.0f - EPSF);
        const float v   = vd[base + t];
        const float x   = (v > 0.5f) ? pvc : (1.0f - pvc);
        av += __logf(x);
    }

    // block-reduce 21 partials: wave shuffle -> LDS -> atomicAdd
    __shared__ float smem[TPB / 64][NACC];
    const int lane = threadIdx.x & 63;
    const int wv   = threadIdx.x >> 6;

    float vals[NACC];
    #pragma unroll
    for (int k = 0; k < 16; ++k) vals[k] = a1[k];
    #pragma unroll
    for (int k = 0; k < 4; ++k)  vals[16 + k] = a2[k];
    vals[20] = av;

    #pragma unroll
    for (int k = 0; k < NACC; ++k) {
        const float r = wave_reduce_sum(vals[k]);
        if (lane == 0) smem[wv][k] = r;
    }
    __syncthreads();
    if (threadIdx.x < NACC) {
        float s = 0.0f;
        #pragma unroll
        for (int w = 0; w < TPB / 64; ++w) s += smem[w][threadIdx.x];
        atomicAdd(&acc[b * NACC + threadIdx.x], s);
    }
}

__global__ void final_kernel(const float* __restrict__ acc,
                             const int* __restrict__ len,
                             float* __restrict__ out)
{
    const int tid = threadIdx.x;   // 64 threads, one wave
    float best = 0.0f, vadn = 0.0f, lensum = 0.0f;
    if (tid < B) {
        const int b = tid;
        const float msum = (float)len[b];
        float Lm[16];
        #pragma unroll
        for (int i = 0; i < 4; ++i)
            #pragma unroll
            for (int j = 0; j < 4; ++j)
                Lm[i * 4 + j] = (-acc[b * NACC + i * 4 + j] - acc[b * NACC + 16 + i]) / msum;

        best = 1e30f;
        #pragma unroll
        for (int p0 = 0; p0 < 4; ++p0)
            #pragma unroll
            for (int p1 = 0; p1 < 4; ++p1) {
                if (p1 == p0) continue;
                #pragma unroll
                for (int p2 = 0; p2 < 4; ++p2) {
                    if (p2 == p0 || p2 == p1) continue;
                    const int p3 = 6 - p0 - p1 - p2;
                    const float s = Lm[p0] + Lm[4 + p1] + Lm[8 + p2] + Lm[12 + p3];
                    best = fminf(best, s);
                }
            }
        best *= 0.25f;                    // mean over S
        vadn   = -acc[b * NACC + 20];     // masked VAD BCE numerator
        lensum = msum;
    }
    best   = wave_reduce_sum(best);
    vadn   = wave_reduce_sum(vadn);
    lensum = wave_reduce_sum(lensum);
    if (tid == 0)
        out[0] = best * (1.0f / B) + 0.5f * (vadn / lensum);
}

extern "C" void kernel_launch(void* const* d_in, const int* in_sizes, int n_in,
                              void* d_out, int out_size, void* d_ws, size_t ws_size,
                              hipStream_t stream) {
    const float4* ps  = (const float4*)d_in[0];     // pred_speakers [B,T,S]
    const float*  pv  = (const float*)d_in[1];      // pred_vad [B,T]
    const float4* lb  = (const float4*)d_in[2];     // labels [B,T,S]
    const float*  vd  = (const float*)d_in[3];      // vad [B,T]
    const int*    len = (const int*)d_in[4];        // lengths [B] int32
    float* acc = (float*)d_ws;                      // B*NACC floats
    float* out = (float*)d_out;

    zero_ws_kernel<<<(B * NACC + 255) / 256, 256, 0, stream>>>(acc);
    partial_kernel<<<B * NCHUNK, TPB, 0, stream>>>(ps, pv, lb, vd, len, acc);
    final_kernel<<<1, 64, 0, stream>>>(acc, len, out);
}